// Round 11
// baseline (197.752 us; speedup 1.0000x reference)
//
#include <hip/hip_runtime.h>
#include <hip/hip_bf16.h>

typedef __bf16 bf16x8 __attribute__((ext_vector_type(8)));
typedef float f32x4 __attribute__((ext_vector_type(4)));
typedef float f32x16 __attribute__((ext_vector_type(16)));
typedef unsigned short ushort_t;
typedef unsigned short ushort8 __attribute__((ext_vector_type(8)));
typedef unsigned int uint4v __attribute__((ext_vector_type(4)));

// ---------- helpers ----------

__device__ inline void gload_lds16(const void* g, void* l) {
  __builtin_amdgcn_global_load_lds(
      (const __attribute__((address_space(1))) void*)g,
      (__attribute__((address_space(3))) void*)l, 16, 0, 0);
}

// fp32 -> bf16 round-to-nearest-even (bit manipulation)
__device__ inline ushort_t f2bf(float f) {
  unsigned int u = __float_as_uint(f);
  unsigned int lsb = (u >> 16) & 1u;
  u += 0x7fffu + lsb;
  return (ushort_t)(u >> 16);
}

// ---------- fused prep: x->bf16, W1->W1^T bf16, W2->W2^T bf16 ----------

__device__ inline void transpose_tile_f32_bf16(
    const float* __restrict__ in, ushort_t* __restrict__ out,
    int R, int C, int cx, int ry, int tid) {
  __shared__ float tile[32][33];
  const int tx = tid & 31, ty = tid >> 5;  // 32 x 8
  const int c0 = cx * 32, r0 = ry * 32;
#pragma unroll
  for (int i = 0; i < 32; i += 8)
    tile[ty + i][tx] = in[(size_t)(r0 + ty + i) * C + c0 + tx];
  __syncthreads();
#pragma unroll
  for (int i = 0; i < 32; i += 8)
    out[(size_t)(c0 + ty + i) * R + r0 + tx] = f2bf(tile[tx][ty + i]);
}

// grid = 2048 (x cvt) + 3072 (W1^T) + 1024 (W2^T) = 6144 blocks
__global__ __launch_bounds__(256) void prep_kernel(
    const float* __restrict__ x, const float* __restrict__ W1,
    const float* __restrict__ W2, ushort_t* __restrict__ xb,
    ushort_t* __restrict__ w1t, ushort_t* __restrict__ w2t) {
  const int bid = blockIdx.x;
  const int tid = threadIdx.x;
  if (bid < 2048) {
    int i = (bid * 256 + tid) * 8;
    float4 a = *(const float4*)&x[i];
    float4 b = *(const float4*)&x[i + 4];
    ushort8 o;
    o[0] = f2bf(a.x); o[1] = f2bf(a.y); o[2] = f2bf(a.z); o[3] = f2bf(a.w);
    o[4] = f2bf(b.x); o[5] = f2bf(b.y); o[6] = f2bf(b.z); o[7] = f2bf(b.w);
    *(ushort8*)&xb[i] = o;
  } else if (bid < 2048 + 3072) {
    const int t = bid - 2048;
    transpose_tile_f32_bf16(W1, w1t, 1024, 3072, t % 96, t / 96, tid);
  } else {
    const int t = bid - 5120;
    transpose_tile_f32_bf16(W2, w2t, 1024, 1024, t % 32, t / 32, tid);
  }
}

// V-part of kqv [4096][3072] -> vt[bh][64 dh][2048 t]  (bf16 transpose)
__global__ __launch_bounds__(256) void transpose_v(
    const ushort_t* __restrict__ kqv, ushort_t* __restrict__ vt) {
  __shared__ ushort_t tile[64 * 64];  // 16B-slot XOR swizzle
  const int tt = blockIdx.x;  // t tile (0..31)
  const int bh = blockIdx.y;  // 0..31
  const int b = bh >> 4, h = bh & 15;
  const int tid = threadIdx.x;
#pragma unroll
  for (int p = 0; p < 2; p++) {
    const int tr = (tid >> 3) + p * 32;
    const int c8 = tid & 7;
    ushort8 v = *(const ushort8*)&kqv[(size_t)(b * 2048 + tt * 64 + tr) * 3072 +
                                      2048 + h * 64 + c8 * 8];
    *(ushort8*)&tile[tr * 64 + ((c8 ^ (tr & 7)) * 8)] = v;
  }
  __syncthreads();
  const int d = tid & 63;
#pragma unroll
  for (int p = 0; p < 2; p++) {
    const int t8 = (tid >> 6) + p * 4;  // 8-t chunk 0..7
    ushort8 o;
#pragma unroll
    for (int j = 0; j < 8; j++) {
      const int t = t8 * 8 + j;
      o[j] = tile[t * 64 + (((d >> 3) ^ (t & 7)) * 8) + (d & 7)];
    }
    *(ushort8*)&vt[(size_t)(bh * 64 + d) * 2048 + tt * 64 + t8 * 8] = o;
  }
}

// ---------- GEMM: C = A @ B (+bias), A[M][K] bf16, BT[N][K] bf16 ----------
// (unchanged — verified pipeline; control)

template <bool OUT_BF16>
__global__ __launch_bounds__(256) void gemm_bt(
    const ushort_t* __restrict__ A, const ushort_t* __restrict__ BT,
    const float* __restrict__ bias, void* __restrict__ Cout,
    int M, int N, int K) {
  __shared__ ushort_t lA[3][128 * 32];  // 24 KB
  __shared__ ushort_t lB[3][128 * 32];  // 24 KB
  const int tid = threadIdx.x;
  const int lane = tid & 63;
  const int wave = tid >> 6;
  const int wr = wave >> 1, wc = wave & 1;
  const int l16 = lane & 15, lhi = lane >> 4;
  const int bx = blockIdx.x, by = blockIdx.y;

  const int srow = tid >> 2;
  const int schunk = (tid & 3) ^ (srow & 3);
  const ushort_t* gA = A + (size_t)(by * 128 + srow) * K + schunk * 8;
  const ushort_t* gB = BT + (size_t)(bx * 128 + srow) * K + schunk * 8;

#define GSTAGE(buf, k0)                                            \
  do {                                                             \
    gload_lds16(gA + (k0), &lA[buf][tid * 8]);                     \
    gload_lds16(gA + (k0) + (size_t)64 * K, &lA[buf][tid * 8 + 2048]); \
    gload_lds16(gB + (k0), &lB[buf][tid * 8]);                     \
    gload_lds16(gB + (k0) + (size_t)64 * K, &lB[buf][tid * 8 + 2048]); \
  } while (0)

  f32x4 acc[4][4] = {};
  const int NK = K >> 5;

  GSTAGE(0, 0);
  GSTAGE(1, 32);

  int cur = 0;
  for (int kt = 0; kt < NK; ++kt) {
    if (kt + 1 < NK) asm volatile("s_waitcnt vmcnt(4)" ::: "memory");
    else             asm volatile("s_waitcnt vmcnt(0)" ::: "memory");
    __builtin_amdgcn_s_barrier();
    asm volatile("" ::: "memory");

    if (kt + 2 < NK) {
      const int pf = (cur + 2 >= 3) ? cur - 1 : cur + 2;
      GSTAGE(pf, (kt + 2) * 32);
    }

    bf16x8 af[4], bfr[4];
#pragma unroll
    for (int m = 0; m < 4; m++) {
      const int row = wr * 64 + m * 16 + l16;
      af[m] = *(const bf16x8*)&lA[cur][row * 32 + ((lhi ^ (row & 3)) * 8)];
    }
#pragma unroll
    for (int n = 0; n < 4; n++) {
      const int row = wc * 64 + n * 16 + l16;
      bfr[n] = *(const bf16x8*)&lB[cur][row * 32 + ((lhi ^ (row & 3)) * 8)];
    }
#pragma unroll
    for (int m = 0; m < 4; m++)
#pragma unroll
      for (int n = 0; n < 4; n++)
        acc[m][n] = __builtin_amdgcn_mfma_f32_16x16x32_bf16(af[m], bfr[n],
                                                            acc[m][n], 0, 0, 0);
    cur = (cur + 1 >= 3) ? 0 : cur + 1;
  }
#undef GSTAGE

  const int r0 = by * 128 + wr * 64 + lhi * 4;
  const int c0 = bx * 128 + wc * 64 + l16;
#pragma unroll
  for (int m = 0; m < 4; m++)
#pragma unroll
    for (int n = 0; n < 4; n++) {
      const int col = c0 + n * 16;
      const float bv = bias[col];
#pragma unroll
      for (int j = 0; j < 4; j++) {
        const int row = r0 + m * 16 + j;
        const float v = acc[m][n][j] + bv;
        if (OUT_BF16)
          ((ushort_t*)Cout)[(size_t)row * N + col] = f2bf(v);
        else
          ((float*)Cout)[(size_t)row * N + col] = v;
      }
    }
}

// ---------- attention (softmax-free, causal) ----------
// v4 = round-9-verified v2 inner loop (42.8us) + DYNAMIC work-stealing:
// 512 persistent blocks (~2/CU, 8 waves/CU sustained) pull (bh, qj) items
// heavy-first from an atomic counter -> LPT balance, no static resonance
// (rounds 6/10 lesson: static block->CU mappings keep producing 1.5-1.9x
// makespan stretch). Item = 64 q-rows; 4 waves = (qs x kb); kb-split with
// epilogue LDS reduce; 2-buffer depth-1 pipeline (verified).

__global__ __launch_bounds__(256) void attn_kernel(
    const ushort_t* __restrict__ kqv, const ushort_t* __restrict__ vt,
    ushort_t* __restrict__ ao, int* __restrict__ counter) {
  __shared__ ushort_t lK[2][64 * 64];   // 16 KB
  __shared__ ushort_t lVT[2][64 * 64];  // 16 KB
  __shared__ int s_item;
  const int tid = threadIdx.x, lane = tid & 63, wave = tid >> 6;
  const int q_rel = lane & 31, hi = lane >> 5;
  const int qs = wave & 1, kb = wave >> 1;

  // staging geometry (item-independent)
  size_t kgo[2], vgo[2];
  int ld[2];
#pragma unroll
  for (int p = 0; p < 2; p++) {
    const int slot = tid + p * 256;
    const int srow = slot >> 3;
    const int scb = (((slot & 7) * 16) ^ ((srow & 7) << 4)) >> 1;  // elem off
    kgo[p] = (size_t)srow * 3072 + scb;
    vgo[p] = (size_t)srow * 2048 + scb;
    ld[p] = slot * 8;
  }

  for (;;) {
    __syncthreads();  // prev item fully done (incl. epilogue LDS reads)
    if (tid == 0) s_item = atomicAdd(counter, 1);
    __syncthreads();
    const int w = s_item;
    if (w >= 1024) break;

    // heavy-first: qj = 31 - (w>>5) in 31..0; bh = w & 31
    const int qj = 31 - (w >> 5);
    const int bh = w & 31;
    const int b = bh >> 4, h = bh & 15;
    const ushort_t* base = kqv + (size_t)b * 2048 * 3072;
    const ushort_t* vbase = vt + (size_t)bh * 64 * 2048;
    const size_t kg0 = kgo[0] + h * 64, kg1 = kgo[1] + h * 64;

    const int wq0 = qj * 64 + qs * 32;
    bf16x8 qf[4];
#pragma unroll
    for (int ds = 0; ds < 4; ds++)
      qf[ds] = *(const bf16x8*)&base[(size_t)(wq0 + q_rel) * 3072 + 1024 + h * 64 +
                                     ds * 16 + hi * 8];

    f32x16 oacc[2] = {};
    const int nkt = qj + 1;

    // prologue: stage tile 0 into buffer 0
    gload_lds16(&base[kg0], &lK[0][ld[0]]);
    gload_lds16(&base[kg1], &lK[0][ld[1]]);
    gload_lds16(&vbase[vgo[0]], &lVT[0][ld[0]]);
    gload_lds16(&vbase[vgo[1]], &lVT[0][ld[1]]);

    int cur = 0;
    for (int kt = 0; kt < nkt; ++kt) {
      asm volatile("s_waitcnt vmcnt(0)" ::: "memory");
      __builtin_amdgcn_s_barrier();
      asm volatile("" ::: "memory");

      if (kt + 1 < nkt) {
        const size_t koff = (size_t)(kt + 1) * 64 * 3072;
        const size_t voff = (size_t)(kt + 1) * 64;
        gload_lds16(&base[koff + kg0], &lK[cur ^ 1][ld[0]]);
        gload_lds16(&base[koff + kg1], &lK[cur ^ 1][ld[1]]);
        gload_lds16(&vbase[voff + vgo[0]], &lVT[cur ^ 1][ld[0]]);
        gload_lds16(&vbase[voff + vgo[1]], &lVT[cur ^ 1][ld[1]]);
      }

      const int kv0 = kt * 64 + kb * 32;
      if (kv0 <= wq0 + 31) {
        f32x16 st = {};
        const int krow = kb * 32 + q_rel;
        const int ksw = krow & 7;
#pragma unroll
        for (int ds = 0; ds < 4; ds++) {
          bf16x8 kf = *(const bf16x8*)&lK[cur][krow * 64 + (((ds * 2 + hi) ^ ksw) * 8)];
          st = __builtin_amdgcn_mfma_f32_32x32x16_bf16(kf, qf[ds], st, 0, 0, 0);
        }
        if (kv0 + 31 > wq0) {
#pragma unroll
          for (int r = 0; r < 16; r++) {
            const int kgl = kv0 + (r & 3) + 8 * (r >> 2) + 4 * hi;
            if (kgl > wq0 + q_rel) st[r] = 0.f;
          }
        }
        unsigned int w0, w1, w2, w3, w4, w5, w6, w7;
        {
          float e0 = st[0], e1 = st[1], e2 = st[2], e3 = st[3];
          float e4 = st[4], e5 = st[5], e6 = st[6], e7 = st[7];
          float e8 = st[8], e9 = st[9], e10 = st[10], e11 = st[11];
          float e12 = st[12], e13 = st[13], e14 = st[14], e15 = st[15];
          asm("v_cvt_pk_bf16_f32 %0, %1, %2" : "=v"(w0) : "v"(e0), "v"(e1));
          asm("v_cvt_pk_bf16_f32 %0, %1, %2" : "=v"(w1) : "v"(e2), "v"(e3));
          asm("v_cvt_pk_bf16_f32 %0, %1, %2" : "=v"(w2) : "v"(e4), "v"(e5));
          asm("v_cvt_pk_bf16_f32 %0, %1, %2" : "=v"(w3) : "v"(e6), "v"(e7));
          asm("v_cvt_pk_bf16_f32 %0, %1, %2" : "=v"(w4) : "v"(e8), "v"(e9));
          asm("v_cvt_pk_bf16_f32 %0, %1, %2" : "=v"(w5) : "v"(e10), "v"(e11));
          asm("v_cvt_pk_bf16_f32 %0, %1, %2" : "=v"(w6) : "v"(e12), "v"(e13));
          asm("v_cvt_pk_bf16_f32 %0, %1, %2" : "=v"(w7) : "v"(e14), "v"(e15));
        }
        asm("v_permlane32_swap_b32 %0, %1" : "+v"(w0), "+v"(w2));
        asm("v_permlane32_swap_b32 %0, %1" : "+v"(w1), "+v"(w3));
        asm("v_permlane32_swap_b32 %0, %1" : "+v"(w4), "+v"(w6));
        asm("v_permlane32_swap_b32 %0, %1" : "+v"(w5), "+v"(w7));
        uint4v u0 = {w0, w1, w2, w3};
        uint4v u1 = {w4, w5, w6, w7};
        bf16x8 pa0 = __builtin_bit_cast(bf16x8, u0);
        bf16x8 pa1 = __builtin_bit_cast(bf16x8, u1);
#pragma unroll
        for (int dt = 0; dt < 2; dt++) {
          const int vrow = dt * 32 + q_rel;
          const int vsw = vrow & 7;
          bf16x8 vf0 = *(const bf16x8*)&lVT[cur][vrow * 64 + (((kb * 4 + hi) ^ vsw) * 8)];
          bf16x8 vf1 = *(const bf16x8*)&lVT[cur][vrow * 64 + (((kb * 4 + 2 + hi) ^ vsw) * 8)];
          oacc[dt] = __builtin_amdgcn_mfma_f32_32x32x16_bf16(pa0, vf0, oacc[dt], 0, 0, 0);
          oacc[dt] = __builtin_amdgcn_mfma_f32_32x32x16_bf16(pa1, vf1, oacc[dt], 0, 0, 0);
        }
      }

      cur ^= 1;
    }

    // epilogue: cross-wave (kb) reduce via LDS f32 scratch (reuses lK)
    __syncthreads();
    float* red = (float*)&lK[0][0];
    if (kb == 1) {
#pragma unroll
      for (int dt = 0; dt < 2; dt++)
#pragma unroll
        for (int r = 0; r < 16; r++)
          red[qs * 2048 + (dt * 16 + r) * 64 + lane] = oacc[dt][r];
    }
    __syncthreads();
    if (kb == 0) {
#pragma unroll
      for (int dt = 0; dt < 2; dt++)
#pragma unroll
        for (int r = 0; r < 16; r++) {
          const float v = oacc[dt][r] + red[qs * 2048 + (dt * 16 + r) * 64 + lane];
          const int q = (r & 3) + 8 * (r >> 2) + 4 * hi;
          const int row = wq0 + q;
          const int col = h * 64 + dt * 32 + q_rel;
          ao[(size_t)(b * 2048 + row) * 1024 + col] = f2bf(v);
        }
    }
  }
}

// ---------- launch ----------

extern "C" void kernel_launch(void* const* d_in, const int* in_sizes, int n_in,
                              void* d_out, int out_size, void* d_ws, size_t ws_size,
                              hipStream_t stream) {
  const float* x  = (const float*)d_in[0];
  const float* W1 = (const float*)d_in[1];
  const float* b1 = (const float*)d_in[2];
  const float* W2 = (const float*)d_in[3];
  const float* b2 = (const float*)d_in[4];
  float* out = (float*)d_out;

  char* ws = (char*)d_ws;
  ushort_t* xb  = (ushort_t*)(ws);                 //  8 MB: x bf16 [4096][1024]
  ushort_t* w1t = (ushort_t*)(ws + 8388608);       //  6 MB: W1^T bf16 [3072][1024]
  ushort_t* w2t = (ushort_t*)(ws + 14680064);      //  2 MB: W2^T bf16 [1024][1024]
  ushort_t* kqv = (ushort_t*)(ws + 16777216);      // 24 MB: kqv bf16 [4096][3072]
  ushort_t* ao  = (ushort_t*)(ws + 41943040);      //  8 MB: attn out bf16 [4096][1024]
  ushort_t* vtb = (ushort_t*)(ws);                 //  8 MB: V^T (aliases xb; xb dead after gemm1)
  int* counter  = (int*)(ws + 67108864);           //  4 B : work-steal counter

  hipMemsetAsync(counter, 0, 4, stream);
  prep_kernel<<<6144, 256, 0, stream>>>(x, W1, W2, xb, w1t, w2t);
  gemm_bt<true ><<<dim3(24, 32), 256, 0, stream>>>(xb, w1t, b1, kqv, 4096, 3072, 1024);
  transpose_v<<<dim3(32, 32), 256, 0, stream>>>(kqv, vtb);
  attn_kernel<<<dim3(512), 256, 0, stream>>>(kqv, vtb, ao, counter);
  gemm_bt<false><<<dim3(8, 32), 256, 0, stream>>>(ao, w2t, b2, out, 4096, 1024, 1024);
}

// Round 12
// 194.444 us; speedup vs baseline: 1.0170x; 1.0170x over previous
//
#include <hip/hip_runtime.h>
#include <hip/hip_bf16.h>

typedef __bf16 bf16x8 __attribute__((ext_vector_type(8)));
typedef float f32x4 __attribute__((ext_vector_type(4)));
typedef float f32x16 __attribute__((ext_vector_type(16)));
typedef unsigned short ushort_t;
typedef unsigned short ushort8 __attribute__((ext_vector_type(8)));
typedef unsigned int uint4v __attribute__((ext_vector_type(4)));

// ---------- helpers ----------

__device__ inline void gload_lds16(const void* g, void* l) {
  __builtin_amdgcn_global_load_lds(
      (const __attribute__((address_space(1))) void*)g,
      (__attribute__((address_space(3))) void*)l, 16, 0, 0);
}

// fp32 -> bf16 round-to-nearest-even (bit manipulation)
__device__ inline ushort_t f2bf(float f) {
  unsigned int u = __float_as_uint(f);
  unsigned int lsb = (u >> 16) & 1u;
  u += 0x7fffu + lsb;
  return (ushort_t)(u >> 16);
}

// ---------- fused prep: x->bf16, W1->W1^T bf16, W2->W2^T bf16 ----------

__device__ inline void transpose_tile_f32_bf16(
    const float* __restrict__ in, ushort_t* __restrict__ out,
    int R, int C, int cx, int ry, int tid) {
  __shared__ float tile[32][33];
  const int tx = tid & 31, ty = tid >> 5;  // 32 x 8
  const int c0 = cx * 32, r0 = ry * 32;
#pragma unroll
  for (int i = 0; i < 32; i += 8)
    tile[ty + i][tx] = in[(size_t)(r0 + ty + i) * C + c0 + tx];
  __syncthreads();
#pragma unroll
  for (int i = 0; i < 32; i += 8)
    out[(size_t)(c0 + ty + i) * R + r0 + tx] = f2bf(tile[tx][ty + i]);
}

// grid = 2048 (x cvt) + 3072 (W1^T) + 1024 (W2^T) = 6144 blocks
__global__ __launch_bounds__(256) void prep_kernel(
    const float* __restrict__ x, const float* __restrict__ W1,
    const float* __restrict__ W2, ushort_t* __restrict__ xb,
    ushort_t* __restrict__ w1t, ushort_t* __restrict__ w2t) {
  const int bid = blockIdx.x;
  const int tid = threadIdx.x;
  if (bid < 2048) {
    int i = (bid * 256 + tid) * 8;
    float4 a = *(const float4*)&x[i];
    float4 b = *(const float4*)&x[i + 4];
    ushort8 o;
    o[0] = f2bf(a.x); o[1] = f2bf(a.y); o[2] = f2bf(a.z); o[3] = f2bf(a.w);
    o[4] = f2bf(b.x); o[5] = f2bf(b.y); o[6] = f2bf(b.z); o[7] = f2bf(b.w);
    *(ushort8*)&xb[i] = o;
  } else if (bid < 2048 + 3072) {
    const int t = bid - 2048;
    transpose_tile_f32_bf16(W1, w1t, 1024, 3072, t % 96, t / 96, tid);
  } else {
    const int t = bid - 5120;
    transpose_tile_f32_bf16(W2, w2t, 1024, 1024, t % 32, t / 32, tid);
  }
}

// V-part of kqv [4096][3072] -> vt[bh][64 dh][2048 t]  (bf16 transpose)
__global__ __launch_bounds__(256) void transpose_v(
    const ushort_t* __restrict__ kqv, ushort_t* __restrict__ vt) {
  __shared__ ushort_t tile[64 * 64];  // 16B-slot XOR swizzle
  const int tt = blockIdx.x;  // t tile (0..31)
  const int bh = blockIdx.y;  // 0..31
  const int b = bh >> 4, h = bh & 15;
  const int tid = threadIdx.x;
#pragma unroll
  for (int p = 0; p < 2; p++) {
    const int tr = (tid >> 3) + p * 32;
    const int c8 = tid & 7;
    ushort8 v = *(const ushort8*)&kqv[(size_t)(b * 2048 + tt * 64 + tr) * 3072 +
                                      2048 + h * 64 + c8 * 8];
    *(ushort8*)&tile[tr * 64 + ((c8 ^ (tr & 7)) * 8)] = v;
  }
  __syncthreads();
  const int d = tid & 63;
#pragma unroll
  for (int p = 0; p < 2; p++) {
    const int t8 = (tid >> 6) + p * 4;  // 8-t chunk 0..7
    ushort8 o;
#pragma unroll
    for (int j = 0; j < 8; j++) {
      const int t = t8 * 8 + j;
      o[j] = tile[t * 64 + (((d >> 3) ^ (t & 7)) * 8) + (d & 7)];
    }
    *(ushort8*)&vt[(size_t)(bh * 64 + d) * 2048 + tt * 64 + t8 * 8] = o;
  }
}

// ---------- GEMM: C = A @ B (+bias), A[M][K] bf16, BT[N][K] bf16 ----------
// (unchanged — verified pipeline; control)

template <bool OUT_BF16>
__global__ __launch_bounds__(256) void gemm_bt(
    const ushort_t* __restrict__ A, const ushort_t* __restrict__ BT,
    const float* __restrict__ bias, void* __restrict__ Cout,
    int M, int N, int K) {
  __shared__ ushort_t lA[3][128 * 32];  // 24 KB
  __shared__ ushort_t lB[3][128 * 32];  // 24 KB
  const int tid = threadIdx.x;
  const int lane = tid & 63;
  const int wave = tid >> 6;
  const int wr = wave >> 1, wc = wave & 1;
  const int l16 = lane & 15, lhi = lane >> 4;
  const int bx = blockIdx.x, by = blockIdx.y;

  const int srow = tid >> 2;
  const int schunk = (tid & 3) ^ (srow & 3);
  const ushort_t* gA = A + (size_t)(by * 128 + srow) * K + schunk * 8;
  const ushort_t* gB = BT + (size_t)(bx * 128 + srow) * K + schunk * 8;

#define GSTAGE(buf, k0)                                            \
  do {                                                             \
    gload_lds16(gA + (k0), &lA[buf][tid * 8]);                     \
    gload_lds16(gA + (k0) + (size_t)64 * K, &lA[buf][tid * 8 + 2048]); \
    gload_lds16(gB + (k0), &lB[buf][tid * 8]);                     \
    gload_lds16(gB + (k0) + (size_t)64 * K, &lB[buf][tid * 8 + 2048]); \
  } while (0)

  f32x4 acc[4][4] = {};
  const int NK = K >> 5;

  GSTAGE(0, 0);
  GSTAGE(1, 32);

  int cur = 0;
  for (int kt = 0; kt < NK; ++kt) {
    if (kt + 1 < NK) asm volatile("s_waitcnt vmcnt(4)" ::: "memory");
    else             asm volatile("s_waitcnt vmcnt(0)" ::: "memory");
    __builtin_amdgcn_s_barrier();
    asm volatile("" ::: "memory");

    if (kt + 2 < NK) {
      const int pf = (cur + 2 >= 3) ? cur - 1 : cur + 2;
      GSTAGE(pf, (kt + 2) * 32);
    }

    bf16x8 af[4], bfr[4];
#pragma unroll
    for (int m = 0; m < 4; m++) {
      const int row = wr * 64 + m * 16 + l16;
      af[m] = *(const bf16x8*)&lA[cur][row * 32 + ((lhi ^ (row & 3)) * 8)];
    }
#pragma unroll
    for (int n = 0; n < 4; n++) {
      const int row = wc * 64 + n * 16 + l16;
      bfr[n] = *(const bf16x8*)&lB[cur][row * 32 + ((lhi ^ (row & 3)) * 8)];
    }
#pragma unroll
    for (int m = 0; m < 4; m++)
#pragma unroll
      for (int n = 0; n < 4; n++)
        acc[m][n] = __builtin_amdgcn_mfma_f32_16x16x32_bf16(af[m], bfr[n],
                                                            acc[m][n], 0, 0, 0);
    cur = (cur + 1 >= 3) ? 0 : cur + 1;
  }
#undef GSTAGE

  const int r0 = by * 128 + wr * 64 + lhi * 4;
  const int c0 = bx * 128 + wc * 64 + l16;
#pragma unroll
  for (int m = 0; m < 4; m++)
#pragma unroll
    for (int n = 0; n < 4; n++) {
      const int col = c0 + n * 16;
      const float bv = bias[col];
#pragma unroll
      for (int j = 0; j < 4; j++) {
        const int row = r0 + m * 16 + j;
        const float v = acc[m][n][j] + bv;
        if (OUT_BF16)
          ((ushort_t*)Cout)[(size_t)row * N + col] = f2bf(v);
        else
          ((float*)Cout)[(size_t)row * N + col] = v;
      }
    }
}

// ---------- attention (softmax-free, causal) ----------
// v5 = round-9-VERIFIED v2 (1024 static blocks, XCD grouping + qj stagger,
// (qs,kb) wave split, cvt_pk+permlane P path, epilogue kb-reduce) with ONE
// change: 3-buffer depth-2 prefetch + counted vmcnt(4) (r5-verified recipe)
// instead of 2-buffer vmcnt(0)-per-tile. Round-11 lesson: locality >
// balance — keep static XCD-local mapping, never dynamic.

__global__ __launch_bounds__(256) void attn_kernel(
    const ushort_t* __restrict__ kqv, const ushort_t* __restrict__ vt,
    ushort_t* __restrict__ ao) {
  __shared__ ushort_t lK[3][64 * 64];   // 24 KB
  __shared__ ushort_t lVT[3][64 * 64];  // 24 KB
  const int tid = threadIdx.x, lane = tid & 63, wave = tid >> 6;
  const int q_rel = lane & 31, hi = lane >> 5;
  const int qs = wave & 1, kb = wave >> 1;
  // bijective XCD swizzle (4 bh per XCD) + per-bh qj stagger (de-resonant)
  const int L = blockIdx.x;
  const int xcd = L & 7, t = L >> 3;        // t in 0..127
  const int bh = xcd * 4 + (t >> 5);
  const int qj = 31 - ((t + bh * 7) & 31);  // heavy-first-ish, staggered
  const int b = bh >> 4, h = bh & 15;
  const ushort_t* base = kqv + (size_t)b * 2048 * 3072;
  const ushort_t* vbase = vt + (size_t)bh * 64 * 2048;

  // staging: 512 slots of 16B (K) + 512 (V); thread covers slot tid, tid+256.
  size_t kg[2], vg[2];
  int ld[2];
#pragma unroll
  for (int p = 0; p < 2; p++) {
    const int slot = tid + p * 256;
    const int srow = slot >> 3;
    const int scb = (((slot & 7) * 16) ^ ((srow & 7) << 4)) >> 1;  // elem off
    kg[p] = (size_t)srow * 3072 + h * 64 + scb;
    vg[p] = (size_t)srow * 2048 + scb;
    ld[p] = slot * 8;
  }

  const int wq0 = qj * 64 + qs * 32;
  bf16x8 qf[4];
#pragma unroll
  for (int ds = 0; ds < 4; ds++)
    qf[ds] = *(const bf16x8*)&base[(size_t)(wq0 + q_rel) * 3072 + 1024 + h * 64 +
                                   ds * 16 + hi * 8];

  f32x16 oacc[2] = {};
  const int nkt = qj + 1;  // causal 64-k tiles (1..32)

  // prologue: stage tile 0 (and tile 1 if it exists)
#pragma unroll
  for (int p = 0; p < 2; p++) {
    gload_lds16(&base[kg[p]], &lK[0][ld[p]]);
    gload_lds16(&vbase[vg[p]], &lVT[0][ld[p]]);
  }
  if (nkt > 1) {
#pragma unroll
    for (int p = 0; p < 2; p++) {
      gload_lds16(&base[(size_t)64 * 3072 + kg[p]], &lK[1][ld[p]]);
      gload_lds16(&vbase[64 + vg[p]], &lVT[1][ld[p]]);
    }
  }

  int cur = 0;
  for (int kt = 0; kt < nkt; ++kt) {
    // own tile-kt loads done; tile kt+1's 4 loads may stay in flight
    if (kt + 1 < nkt) asm volatile("s_waitcnt vmcnt(4)" ::: "memory");
    else              asm volatile("s_waitcnt vmcnt(0)" ::: "memory");
    __builtin_amdgcn_s_barrier();
    asm volatile("" ::: "memory");

    // prefetch kt+2 into buffer last read at kt-1 (closed by barrier above)
    if (kt + 2 < nkt) {
      const int pf = (cur + 2 >= 3) ? cur - 1 : cur + 2;
      const size_t koff = (size_t)(kt + 2) * 64 * 3072;
      const size_t voff = (size_t)(kt + 2) * 64;
#pragma unroll
      for (int p = 0; p < 2; p++) {
        gload_lds16(&base[koff + kg[p]], &lK[pf][ld[p]]);
        gload_lds16(&vbase[voff + vg[p]], &lVT[pf][ld[p]]);
      }
    }

    const int kv0 = kt * 64 + kb * 32;
    if (kv0 <= wq0 + 31) {
      // St = K·Q^T (32x32): lane holds St[k][q_rel], k=(r&3)+8*(r>>2)+4*hi
      f32x16 st = {};
      const int krow = kb * 32 + q_rel;
      const int ksw = krow & 7;
#pragma unroll
      for (int ds = 0; ds < 4; ds++) {
        bf16x8 kf = *(const bf16x8*)&lK[cur][krow * 64 + (((ds * 2 + hi) ^ ksw) * 8)];
        st = __builtin_amdgcn_mfma_f32_32x32x16_bf16(kf, qf[ds], st, 0, 0, 0);
      }
      if (kv0 + 31 > wq0) {  // causal mask
#pragma unroll
        for (int r = 0; r < 16; r++) {
          const int kgl = kv0 + (r & 3) + 8 * (r >> 2) + 4 * hi;
          if (kgl > wq0 + q_rel) st[r] = 0.f;
        }
      }
      // T12: f32 -> packed bf16 + permlane32_swap -> PV A-frags
      unsigned int w0, w1, w2, w3, w4, w5, w6, w7;
      {
        float e0 = st[0], e1 = st[1], e2 = st[2], e3 = st[3];
        float e4 = st[4], e5 = st[5], e6 = st[6], e7 = st[7];
        float e8 = st[8], e9 = st[9], e10 = st[10], e11 = st[11];
        float e12 = st[12], e13 = st[13], e14 = st[14], e15 = st[15];
        asm("v_cvt_pk_bf16_f32 %0, %1, %2" : "=v"(w0) : "v"(e0), "v"(e1));
        asm("v_cvt_pk_bf16_f32 %0, %1, %2" : "=v"(w1) : "v"(e2), "v"(e3));
        asm("v_cvt_pk_bf16_f32 %0, %1, %2" : "=v"(w2) : "v"(e4), "v"(e5));
        asm("v_cvt_pk_bf16_f32 %0, %1, %2" : "=v"(w3) : "v"(e6), "v"(e7));
        asm("v_cvt_pk_bf16_f32 %0, %1, %2" : "=v"(w4) : "v"(e8), "v"(e9));
        asm("v_cvt_pk_bf16_f32 %0, %1, %2" : "=v"(w5) : "v"(e10), "v"(e11));
        asm("v_cvt_pk_bf16_f32 %0, %1, %2" : "=v"(w6) : "v"(e12), "v"(e13));
        asm("v_cvt_pk_bf16_f32 %0, %1, %2" : "=v"(w7) : "v"(e14), "v"(e15));
      }
      asm("v_permlane32_swap_b32 %0, %1" : "+v"(w0), "+v"(w2));
      asm("v_permlane32_swap_b32 %0, %1" : "+v"(w1), "+v"(w3));
      asm("v_permlane32_swap_b32 %0, %1" : "+v"(w4), "+v"(w6));
      asm("v_permlane32_swap_b32 %0, %1" : "+v"(w5), "+v"(w7));
      uint4v u0 = {w0, w1, w2, w3};  // P[q][k = kv0 + hi*8 + 0..7]
      uint4v u1 = {w4, w5, w6, w7};  // P[q][k = kv0 + 16 + hi*8 + 0..7]
      bf16x8 pa0 = __builtin_bit_cast(bf16x8, u0);
      bf16x8 pa1 = __builtin_bit_cast(bf16x8, u1);
#pragma unroll
      for (int dt = 0; dt < 2; dt++) {
        const int vrow = dt * 32 + q_rel;
        const int vsw = vrow & 7;
        bf16x8 vf0 = *(const bf16x8*)&lVT[cur][vrow * 64 + (((kb * 4 + hi) ^ vsw) * 8)];
        bf16x8 vf1 = *(const bf16x8*)&lVT[cur][vrow * 64 + (((kb * 4 + 2 + hi) ^ vsw) * 8)];
        oacc[dt] = __builtin_amdgcn_mfma_f32_32x32x16_bf16(pa0, vf0, oacc[dt], 0, 0, 0);
        oacc[dt] = __builtin_amdgcn_mfma_f32_32x32x16_bf16(pa1, vf1, oacc[dt], 0, 0, 0);
      }
    }

    cur = (cur + 1 >= 3) ? 0 : cur + 1;
  }

  // epilogue: cross-wave (kb) reduce via LDS f32 scratch (reuses lK[0])
  __syncthreads();
  float* red = (float*)&lK[0][0];
  if (kb == 1) {
#pragma unroll
    for (int dt = 0; dt < 2; dt++)
#pragma unroll
      for (int r = 0; r < 16; r++)
        red[qs * 2048 + (dt * 16 + r) * 64 + lane] = oacc[dt][r];
  }
  __syncthreads();
  if (kb == 0) {
#pragma unroll
    for (int dt = 0; dt < 2; dt++)
#pragma unroll
      for (int r = 0; r < 16; r++) {
        const float v = oacc[dt][r] + red[qs * 2048 + (dt * 16 + r) * 64 + lane];
        const int q = (r & 3) + 8 * (r >> 2) + 4 * hi;
        const int row = wq0 + q;
        const int col = h * 64 + dt * 32 + q_rel;
        ao[(size_t)(b * 2048 + row) * 1024 + col] = f2bf(v);
      }
  }
}

// ---------- launch ----------

extern "C" void kernel_launch(void* const* d_in, const int* in_sizes, int n_in,
                              void* d_out, int out_size, void* d_ws, size_t ws_size,
                              hipStream_t stream) {
  const float* x  = (const float*)d_in[0];
  const float* W1 = (const float*)d_in[1];
  const float* b1 = (const float*)d_in[2];
  const float* W2 = (const float*)d_in[3];
  const float* b2 = (const float*)d_in[4];
  float* out = (float*)d_out;

  char* ws = (char*)d_ws;
  ushort_t* xb  = (ushort_t*)(ws);                 //  8 MB: x bf16 [4096][1024]
  ushort_t* w1t = (ushort_t*)(ws + 8388608);       //  6 MB: W1^T bf16 [3072][1024]
  ushort_t* w2t = (ushort_t*)(ws + 14680064);      //  2 MB: W2^T bf16 [1024][1024]
  ushort_t* kqv = (ushort_t*)(ws + 16777216);      // 24 MB: kqv bf16 [4096][3072]
  ushort_t* ao  = (ushort_t*)(ws + 41943040);      //  8 MB: attn out bf16 [4096][1024]
  ushort_t* vtb = (ushort_t*)(ws);                 //  8 MB: V^T (aliases xb; xb dead after gemm1)

  prep_kernel<<<6144, 256, 0, stream>>>(x, W1, W2, xb, w1t, w2t);
  gemm_bt<true ><<<dim3(24, 32), 256, 0, stream>>>(xb, w1t, b1, kqv, 4096, 3072, 1024);
  transpose_v<<<dim3(32, 32), 256, 0, stream>>>(kqv, vtb);
  attn_kernel<<<dim3(1024), 256, 0, stream>>>(kqv, vtb, ao);
  gemm_bt<false><<<dim3(8, 32), 256, 0, stream>>>(ao, w2t, b2, out, 4096, 1024, 1024);
}